// Round 4
// baseline (266.254 us; speedup 1.0000x reference)
//
#include <hip/hip_runtime.h>

typedef unsigned short u16;
typedef unsigned int u32;
typedef __attribute__((ext_vector_type(8))) short bf16x8;
typedef __attribute__((ext_vector_type(4))) float f32x4;
typedef __attribute__((ext_vector_type(16))) float f32x16;
typedef __attribute__((ext_vector_type(4))) u32 u32x4;

#define D_MODEL 1024
#define NHEAD 16
#define DHEAD 64
#define SEQ 2048
#define BATCH 4
#define MTOT (BATCH * SEQ) /* 8192 */
#define LOG2E 1.4426950408889634f

#define MFMA16(A, B, C) __builtin_amdgcn_mfma_f32_16x16x32_bf16((A), (B), (C), 0, 0, 0)
#define MFMA32(A, B, C) __builtin_amdgcn_mfma_f32_32x32x16_bf16((A), (B), (C), 0, 0, 0)

__device__ __forceinline__ u16 f2bf(float f) {
  u32 u = __builtin_bit_cast(u32, f);
  u = (u + 0x7FFFu + ((u >> 16) & 1u)) >> 16;
  return (u16)u;
}

// async global->LDS, 16B per lane. lds must be wave-uniform; g is per-lane.
__device__ __forceinline__ void async_copy16(void* lds, const void* g) {
  __builtin_amdgcn_global_load_lds(
      (const __attribute__((address_space(1))) u32*)g,
      (__attribute__((address_space(3))) u32*)lds, 16, 0, 0);
}

__device__ __forceinline__ u32 cvtpk_bf16(float lo, float hi) {
  u32 r;
  asm("v_cvt_pk_bf16_f32 %0, %1, %2" : "=v"(r) : "v"(lo), "v"(hi));
  return r;
}
// swaps a.hi32lanes <-> b.lo32lanes
__device__ __forceinline__ void permswap(u32& a, u32& b) {
  asm("v_permlane32_swap_b32 %0, %1" : "+v"(a), "+v"(b));
}

// ---------------- fp32 -> bf16 convert (two tensors per launch) ----------------
__global__ void cvt2(const float* __restrict__ s0, u16* __restrict__ d0,
                     const float* __restrict__ s1, u16* __restrict__ d1, int n4) {
  int i = blockIdx.x * blockDim.x + threadIdx.x;
  int st = gridDim.x * blockDim.x;
  for (; i < 2 * n4; i += st) {
    const float* s = (i < n4) ? s0 : s1;
    u16* d = (i < n4) ? d0 : d1;
    int j = (i < n4) ? i : (i - n4);
    float4 v = ((const float4*)s)[j];
    ushort4 o;
    o.x = f2bf(v.x); o.y = f2bf(v.y); o.z = f2bf(v.z); o.w = f2bf(v.w);
    ((ushort4*)d)[j] = o;
  }
}

// ---------------- NT GEMM: C[m][n] = sum_k A[m][k]*B[n][k] + bias[n] ----------------
// SM: 1 = f32 row-major out, 2 = bf16 transposed V out, 3 = bf16 + qk-norm*sMul (per 64-col head)
#define BM 128
#define BN 128
#define BKG 64

template <int SM>
__global__ __launch_bounds__(256, 2) void gemm_bt(const u16* __restrict__ A,
                                                  const u16* __restrict__ Bw,
                                                  const float* __restrict__ bias,
                                                  void* __restrict__ Cout,
                                                  int M, int N, int K, float sMul) {
  __shared__ u16 As[BM * BKG]; // 16KB, rows 128B, granule-swizzled g^=(row&7)
  __shared__ u16 Bs[BN * BKG]; // 16KB
  const int tid = threadIdx.x;
  const int l = tid & 63;
  const int wid = tid >> 6;
  const int nwg = gridDim.x;
  const int bid = blockIdx.x;
  const int cpx = nwg >> 3;
  const int swz = (bid & 7) * cpx + (bid >> 3);
  const int ntile = N / BN;
  const int m0 = (swz / ntile) * BM;
  const int n0 = (swz % ntile) * BN;
  const int wr = wid >> 1, wc = wid & 1;
  const int r = l & 15, kg = l >> 4;
  f32x4 acc[4][4] = {};
  char* AsB = (char*)As;
  char* BsB = (char*)Bs;
  const int arow = l >> 3;
  const int agran = (l & 7) ^ arow;

  for (int kt = 0; kt < K; kt += BKG) {
#pragma unroll
    for (int cc = 0; cc < 4; ++cc) {
      int c = wid + (cc << 2);
      int rowi = (c << 3) + arow;
      const char* ga = (const char*)A + ((size_t)(m0 + rowi) * K + kt) * 2 + agran * 16;
      async_copy16(AsB + c * 1024, ga);
      const char* gb = (const char*)Bw + ((size_t)(n0 + rowi) * K + kt) * 2 + agran * 16;
      async_copy16(BsB + c * 1024, gb);
    }
    __syncthreads();
#pragma unroll
    for (int half = 0; half < 2; ++half) {
      const int g = ((half << 2) + kg) ^ (r & 7);
      bf16x8 af[4], bf[4];
#pragma unroll
      for (int i = 0; i < 4; ++i) {
        af[i] = *(const bf16x8*)(AsB + (wr * 64 + i * 16 + r) * 128 + g * 16);
        bf[i] = *(const bf16x8*)(BsB + (wc * 64 + i * 16 + r) * 128 + g * 16);
      }
#pragma unroll
      for (int i = 0; i < 4; ++i)
#pragma unroll
        for (int j = 0; j < 4; ++j)
          acc[i][j] = MFMA16(af[i], bf[j], acc[i][j]);
    }
    __syncthreads();
  }

  if (SM == 3) {
    // bf16 out + L2-normalize each row's 64-col head group, then * sMul
    u16* C = (u16*)Cout;
    float bvj[4];
#pragma unroll
    for (int j = 0; j < 4; ++j) bvj[j] = bias[n0 + wc * 64 + j * 16 + r];
#pragma unroll
    for (int i = 0; i < 4; ++i) {
      const int row0 = m0 + wr * 64 + i * 16 + kg * 4;
#pragma unroll
      for (int jj = 0; jj < 4; ++jj) {
        float t[4];
        float s2 = 0.f;
#pragma unroll
        for (int j = 0; j < 4; ++j) {
          t[j] = acc[i][j][jj] + bvj[j];
          s2 += t[j] * t[j];
        }
        s2 += __shfl_xor(s2, 1);
        s2 += __shfl_xor(s2, 2);
        s2 += __shfl_xor(s2, 4);
        s2 += __shfl_xor(s2, 8);
        const float inv = sMul / (sqrtf(s2) + 1e-6f);
#pragma unroll
        for (int j = 0; j < 4; ++j)
          C[(size_t)(row0 + jj) * N + n0 + wc * 64 + j * 16 + r] = f2bf(t[j] * inv);
      }
    }
    return;
  }

#pragma unroll
  for (int i = 0; i < 4; ++i) {
#pragma unroll
    for (int j = 0; j < 4; ++j) {
      const int col = n0 + wc * 64 + j * 16 + r;
      const float bv = bias[col];
      const int row0 = m0 + wr * 64 + i * 16 + kg * 4;
      if (SM == 1) {
        float* C = (float*)Cout;
#pragma unroll
        for (int jj = 0; jj < 4; ++jj)
          C[(size_t)(row0 + jj) * N + col] = acc[i][j][jj] + bv;
      } else {
        // V transposed store: Vt[(b*16+h)*64 + dh][tok], 4 consecutive tok per lane
        u16* C = (u16*)Cout;
        const int hh = col >> 6, dh = col & 63;
        const int bb = row0 >> 11, tok = row0 & 2047;
        ushort4 o;
        o.x = f2bf(acc[i][j][0] + bv);
        o.y = f2bf(acc[i][j][1] + bv);
        o.z = f2bf(acc[i][j][2] + bv);
        o.w = f2bf(acc[i][j][3] + bv);
        *(ushort4*)(C + ((size_t)((bb * 16 + hh) * 64 + dh) * SEQ + tok)) = o;
      }
    }
  }
}

// ---------------- flash attention v4 ----------------
// KVB=64, 4 blocks/CU, conflict-free swizzle, static 2x-unrolled double buffer,
// strength-reduced stage pointers, Q pre-scaled by log2e (exp2 only, e-factor cancels),
// opaque zero-C regs for the S MFMAs.
#define KVB 64
#define NT (SEQ / KVB)

__global__ __launch_bounds__(256, 4) void attn_kernel(const u16* __restrict__ Q,
                                                      const u16* __restrict__ K,
                                                      const u16* __restrict__ Vt,
                                                      u16* __restrict__ O) {
  __shared__ alignas(16) u16 KsA[KVB * 64], KsB[KVB * 64]; // 8KB each
  __shared__ alignas(16) u16 VsA[64 * KVB], VsB[64 * KVB]; // 8KB each
  const int tid = threadIdx.x;
  const int l = tid & 63;
  const int wid = tid >> 6;
  const int qg = l & 31;     // q row within wave
  const int half = l >> 5;
  // XCD-chunked grid: each XCD gets 128 consecutive swz = 8 bh values (K/V L2-resident)
  const int bid = blockIdx.x;
  const int swz = (bid & 7) * 128 + (bid >> 3);
  const int qt = swz & 15;   // 0..15
  const int bh = swz >> 4;   // 0..63
  const int b = bh >> 4, h = bh & 15;

  // ---- stage geometry: wave handles K chunks {wid, wid+4} and V chunks {wid, wid+4}
  const int srow = l >> 3, slot = l & 7;
  const int r0 = (wid << 3) + srow;        // rows 0..63 (chunk c0 = wid)
  const int r1 = ((wid + 4) << 3) + srow;  // rows (chunk c1 = wid+4)
  const int sw0 = (r0 ^ (r0 >> 3)) & 7;
  const int sw1 = (r1 ^ (r1 >> 3)) & 7;
  const u16* pK0 = K + ((size_t)(b * SEQ) + r0) * D_MODEL + h * 64 + (slot ^ sw0) * 8;
  const u16* pK1 = K + ((size_t)(b * SEQ) + r1) * D_MODEL + h * 64 + (slot ^ sw1) * 8;
  const u16* pV0 = Vt + ((size_t)(bh * 64) + r0) * SEQ + (slot ^ sw0) * 8;
  const u16* pV1 = Vt + ((size_t)(bh * 64) + r1) * SEQ + (slot ^ sw1) * 8;
  const int ldsc0 = wid * 1024, ldsc1 = (wid + 4) * 1024;

  // Q fragments (pre-scaled by log2e at GEMM): col=q=l&31, k = dc*16 + half*8 + e
  bf16x8 qf[4];
  {
    const u16* q0 = Q + ((size_t)(b * SEQ + qt * 128 + wid * 32 + qg)) * D_MODEL + h * 64 + half * 8;
#pragma unroll
    for (int dc = 0; dc < 4; ++dc) qf[dc] = *(const bf16x8*)(q0 + dc * 16);
  }
  // opaque zero C-tuple (stays live in 16 VGPRs; avoids per-tile acc zero-init)
  float z0 = 0.f;
  asm volatile("" : "+v"(z0));
  f32x16 zc;
#pragma unroll
  for (int i = 0; i < 16; ++i) zc[i] = z0;

  f32x16 oacc[2] = {};
  float lrun = 0.f;

  auto stage = [&](u16* KsX, u16* VsX) {
    async_copy16((char*)KsX + ldsc0, pK0);
    async_copy16((char*)KsX + ldsc1, pK1);
    async_copy16((char*)VsX + ldsc0, pV0);
    async_copy16((char*)VsX + ldsc1, pV1);
    pK0 += (size_t)KVB * D_MODEL;
    pK1 += (size_t)KVB * D_MODEL;
    pV0 += KVB;
    pV1 += KVB;
  };

  auto process = [&](const u16* KsX, const u16* VsX) {
    const char* KsC = (const char*)KsX;
    const char* VsC = (const char*)VsX;
    // S^T[kv][q] = K·Q' (Q' = log2e * q-hat): lane holds q=l&31, 32 kv over 16 regs x 2 tiles
    f32x16 st[2];
    __builtin_amdgcn_s_setprio(1);
#pragma unroll
    for (int t32 = 0; t32 < 2; ++t32) {
      const int rowK = t32 * 32 + qg;
      const int swk = (rowK ^ (rowK >> 3)) & 7;
      bf16x8 kf0 = *(const bf16x8*)(KsC + rowK * 128 + (half ^ swk) * 16);
      st[t32] = MFMA32(kf0, qf[0], zc);
#pragma unroll
      for (int dc = 1; dc < 4; ++dc) {
        bf16x8 kf = *(const bf16x8*)(KsC + rowK * 128 + ((dc * 2 + half) ^ swk) * 16);
        st[t32] = MFMA32(kf, qf[dc], st[t32]);
      }
    }
    __builtin_amdgcn_s_setprio(0);

    // p = exp2(s')  (global factor e^1 cancels between numerator and denominator)
    float rs0 = 0.f, rs1 = 0.f, rs2 = 0.f, rs3 = 0.f;
#pragma unroll
    for (int t32 = 0; t32 < 2; ++t32)
#pragma unroll
      for (int rr = 0; rr < 16; rr += 4) {
        float p0 = __builtin_amdgcn_exp2f(st[t32][rr + 0]);
        float p1 = __builtin_amdgcn_exp2f(st[t32][rr + 1]);
        float p2 = __builtin_amdgcn_exp2f(st[t32][rr + 2]);
        float p3 = __builtin_amdgcn_exp2f(st[t32][rr + 3]);
        st[t32][rr + 0] = p0; st[t32][rr + 1] = p1;
        st[t32][rr + 2] = p2; st[t32][rr + 3] = p3;
        rs0 += p0; rs1 += p1; rs2 += p2; rs3 += p3;
      }
    lrun += (rs0 + rs1) + (rs2 + rs3);

    // PV: O^T[dh][q] += V^T[dh][kv] * P[q][kv]
#pragma unroll
    for (int t32 = 0; t32 < 2; ++t32) {
#pragma unroll
      for (int cc = 0; cc < 2; ++cc) {
        const int base = cc * 8;
        u32 wA = cvtpk_bf16(st[t32][base + 0], st[t32][base + 1]);
        u32 wB = cvtpk_bf16(st[t32][base + 2], st[t32][base + 3]);
        u32 wC = cvtpk_bf16(st[t32][base + 4], st[t32][base + 5]);
        u32 wD = cvtpk_bf16(st[t32][base + 6], st[t32][base + 7]);
        permswap(wA, wC);
        permswap(wB, wD);
        u32x4 pw = {wA, wB, wC, wD};
        bf16x8 pf = __builtin_bit_cast(bf16x8, pw);
        const int qw = ((t32 * 2 + cc) << 1) + half;
        __builtin_amdgcn_s_setprio(1);
#pragma unroll
        for (int dt = 0; dt < 2; ++dt) {
          const int rowV = dt * 32 + qg;
          const int pp = qw ^ ((rowV ^ (rowV >> 3)) & 7);
          bf16x8 vf = *(const bf16x8*)(VsC + rowV * 128 + pp * 16);
          oacc[dt] = MFMA32(vf, pf, oacc[dt]);
        }
        __builtin_amdgcn_s_setprio(0);
      }
    }
  };

  stage(KsA, VsA); // tile 0
  __syncthreads();
  for (int t = 0; t < NT; t += 2) {
    stage(KsB, VsB);                  // tile t+1
    process(KsA, VsA);                // tile t
    __syncthreads();
    if (t + 2 < NT) stage(KsA, VsA);  // tile t+2
    process(KsB, VsB);                // tile t+1
    __syncthreads();
  }

  // epilogue: denom = own-half sum + other-half sum; pack pairs, u32 stores
  lrun += __shfl_xor(lrun, 32);
  const float inv = 1.0f / lrun;
  u32* orow = (u32*)(O + ((size_t)(b * SEQ + qt * 128 + wid * 32 + qg)) * D_MODEL + h * 64);
#pragma unroll
  for (int dt = 0; dt < 2; ++dt)
#pragma unroll
    for (int w = 0; w < 8; ++w) {
      const int dh = dt * 32 + (w & 1) * 2 + 8 * (w >> 1) + 4 * half;
      u32 pk = cvtpk_bf16(oacc[dt][2 * w] * inv, oacc[dt][2 * w + 1] * inv);
      orow[dh >> 1] = pk;
    }
}

// ---------------- launch ----------------
extern "C" void kernel_launch(void* const* d_in, const int* in_sizes, int n_in,
                              void* d_out, int out_size, void* d_ws, size_t ws_size,
                              hipStream_t stream) {
  const float* x   = (const float*)d_in[0];
  const float* ctx = (const float*)d_in[1];
  const float* Wq  = (const float*)d_in[2];
  const float* bq  = (const float*)d_in[3];
  const float* Wk  = (const float*)d_in[4];
  const float* bk  = (const float*)d_in[5];
  const float* Wv  = (const float*)d_in[6];
  const float* bv  = (const float*)d_in[7];
  const float* Wo  = (const float*)d_in[8];
  const float* bo  = (const float*)d_in[9];
  float* out = (float*)d_out;

  const size_t NTOK = (size_t)MTOT * D_MODEL; // 8M elems
  const size_t WSZ = (size_t)D_MODEL * D_MODEL;
  u16* xb  = (u16*)d_ws;       // x bf16; later reused as attention output
  u16* cb  = xb + NTOK;
  u16* wqb = cb + NTOK;
  u16* wkb = wqb + WSZ;
  u16* wvb = wkb + WSZ;
  u16* wob = wvb + WSZ;
  u16* Qb  = wob + WSZ;
  u16* Kb  = Qb + NTOK;
  u16* Vtb = Kb + NTOK;        // [b*16+h][dh][tok]
  (void)in_sizes; (void)n_in; (void)out_size; (void)ws_size;

  dim3 blk(256);
  cvt2<<<2048, blk, 0, stream>>>(x, xb, ctx, cb, (int)(NTOK / 4));
  cvt2<<<512, blk, 0, stream>>>(Wq, wqb, Wk, wkb, (int)(WSZ / 4));
  cvt2<<<512, blk, 0, stream>>>(Wv, wvb, Wo, wob, (int)(WSZ / 4));

  gemm_bt<3><<<512, blk, 0, stream>>>(xb, wqb, bq, Qb, MTOT, D_MODEL, D_MODEL, LOG2E);
  gemm_bt<3><<<512, blk, 0, stream>>>(cb, wkb, bk, Kb, MTOT, D_MODEL, D_MODEL, 1.0f);
  gemm_bt<2><<<512, blk, 0, stream>>>(cb, wvb, bv, Vtb, MTOT, D_MODEL, D_MODEL, 0.f);

  attn_kernel<<<1024, blk, 0, stream>>>(Qb, Kb, Vtb, xb);

  gemm_bt<1><<<512, blk, 0, stream>>>(xb, wob, bo, out, MTOT, D_MODEL, D_MODEL, 0.f);
}

// Round 5
// 197.686 us; speedup vs baseline: 1.3469x; 1.3469x over previous
//
#include <hip/hip_runtime.h>

typedef unsigned short u16;
typedef unsigned int u32;
typedef __attribute__((ext_vector_type(8))) short bf16x8;
typedef __attribute__((ext_vector_type(4))) float f32x4;
typedef __attribute__((ext_vector_type(16))) float f32x16;
typedef __attribute__((ext_vector_type(4))) u32 u32x4;

#define D_MODEL 1024
#define NHEAD 16
#define DHEAD 64
#define SEQ 2048
#define BATCH 4
#define MTOT (BATCH * SEQ) /* 8192 */
#define LOG2E 1.4426950408889634f

#define MFMA16(A, B, C) __builtin_amdgcn_mfma_f32_16x16x32_bf16((A), (B), (C), 0, 0, 0)
#define MFMA32(A, B, C) __builtin_amdgcn_mfma_f32_32x32x16_bf16((A), (B), (C), 0, 0, 0)

__device__ __forceinline__ u16 f2bf(float f) {
  u32 u = __builtin_bit_cast(u32, f);
  u = (u + 0x7FFFu + ((u >> 16) & 1u)) >> 16;
  return (u16)u;
}

// async global->LDS, 16B per lane. lds must be wave-uniform; g is per-lane.
__device__ __forceinline__ void async_copy16(void* lds, const void* g) {
  __builtin_amdgcn_global_load_lds(
      (const __attribute__((address_space(1))) u32*)g,
      (__attribute__((address_space(3))) u32*)lds, 16, 0, 0);
}

__device__ __forceinline__ u32 cvtpk_bf16(float lo, float hi) {
  u32 r;
  asm("v_cvt_pk_bf16_f32 %0, %1, %2" : "=v"(r) : "v"(lo), "v"(hi));
  return r;
}
// swaps a.hi32lanes <-> b.lo32lanes
__device__ __forceinline__ void permswap(u32& a, u32& b) {
  asm("v_permlane32_swap_b32 %0, %1" : "+v"(a), "+v"(b));
}

// ---------------- fp32 -> bf16 convert (two tensors per launch) ----------------
__global__ void cvt2(const float* __restrict__ s0, u16* __restrict__ d0,
                     const float* __restrict__ s1, u16* __restrict__ d1, int n4) {
  int i = blockIdx.x * blockDim.x + threadIdx.x;
  int st = gridDim.x * blockDim.x;
  for (; i < 2 * n4; i += st) {
    const float* s = (i < n4) ? s0 : s1;
    u16* d = (i < n4) ? d0 : d1;
    int j = (i < n4) ? i : (i - n4);
    float4 v = ((const float4*)s)[j];
    ushort4 o;
    o.x = f2bf(v.x); o.y = f2bf(v.y); o.z = f2bf(v.z); o.w = f2bf(v.w);
    ((ushort4*)d)[j] = o;
  }
}

// ---------------- NT GEMM: C[m][n] = sum_k A[m][k]*B[n][k] + bias[n] ----------------
// SM: 1 = f32 row-major out, 2 = bf16 transposed V out, 3 = bf16 + qk-norm*sMul (per 64-col head)
#define BM 128
#define BN 128
#define BKG 64

template <int SM>
__global__ __launch_bounds__(256, 2) void gemm_bt(const u16* __restrict__ A,
                                                  const u16* __restrict__ Bw,
                                                  const float* __restrict__ bias,
                                                  void* __restrict__ Cout,
                                                  int M, int N, int K, float sMul) {
  __shared__ u16 As[BM * BKG]; // 16KB, rows 128B, granule-swizzled g^=(row&7)
  __shared__ u16 Bs[BN * BKG]; // 16KB
  const int tid = threadIdx.x;
  const int l = tid & 63;
  const int wid = tid >> 6;
  const int nwg = gridDim.x;
  const int bid = blockIdx.x;
  const int cpx = nwg >> 3;
  const int swz = (bid & 7) * cpx + (bid >> 3);
  const int ntile = N / BN;
  const int m0 = (swz / ntile) * BM;
  const int n0 = (swz % ntile) * BN;
  const int wr = wid >> 1, wc = wid & 1;
  const int r = l & 15, kg = l >> 4;
  f32x4 acc[4][4] = {};
  char* AsB = (char*)As;
  char* BsB = (char*)Bs;
  const int arow = l >> 3;
  const int agran = (l & 7) ^ arow;

  for (int kt = 0; kt < K; kt += BKG) {
#pragma unroll
    for (int cc = 0; cc < 4; ++cc) {
      int c = wid + (cc << 2);
      int rowi = (c << 3) + arow;
      const char* ga = (const char*)A + ((size_t)(m0 + rowi) * K + kt) * 2 + agran * 16;
      async_copy16(AsB + c * 1024, ga);
      const char* gb = (const char*)Bw + ((size_t)(n0 + rowi) * K + kt) * 2 + agran * 16;
      async_copy16(BsB + c * 1024, gb);
    }
    __syncthreads();
#pragma unroll
    for (int half = 0; half < 2; ++half) {
      const int g = ((half << 2) + kg) ^ (r & 7);
      bf16x8 af[4], bf[4];
#pragma unroll
      for (int i = 0; i < 4; ++i) {
        af[i] = *(const bf16x8*)(AsB + (wr * 64 + i * 16 + r) * 128 + g * 16);
        bf[i] = *(const bf16x8*)(BsB + (wc * 64 + i * 16 + r) * 128 + g * 16);
      }
#pragma unroll
      for (int i = 0; i < 4; ++i)
#pragma unroll
        for (int j = 0; j < 4; ++j)
          acc[i][j] = MFMA16(af[i], bf[j], acc[i][j]);
    }
    __syncthreads();
  }

  if (SM == 3) {
    // bf16 out + L2-normalize each row's 64-col head group, then * sMul
    u16* C = (u16*)Cout;
    float bvj[4];
#pragma unroll
    for (int j = 0; j < 4; ++j) bvj[j] = bias[n0 + wc * 64 + j * 16 + r];
#pragma unroll
    for (int i = 0; i < 4; ++i) {
      const int row0 = m0 + wr * 64 + i * 16 + kg * 4;
#pragma unroll
      for (int jj = 0; jj < 4; ++jj) {
        float t[4];
        float s2 = 0.f;
#pragma unroll
        for (int j = 0; j < 4; ++j) {
          t[j] = acc[i][j][jj] + bvj[j];
          s2 += t[j] * t[j];
        }
        s2 += __shfl_xor(s2, 1);
        s2 += __shfl_xor(s2, 2);
        s2 += __shfl_xor(s2, 4);
        s2 += __shfl_xor(s2, 8);
        const float inv = sMul / (sqrtf(s2) + 1e-6f);
#pragma unroll
        for (int j = 0; j < 4; ++j)
          C[(size_t)(row0 + jj) * N + n0 + wc * 64 + j * 16 + r] = f2bf(t[j] * inv);
      }
    }
    return;
  }

#pragma unroll
  for (int i = 0; i < 4; ++i) {
#pragma unroll
    for (int j = 0; j < 4; ++j) {
      const int col = n0 + wc * 64 + j * 16 + r;
      const float bv = bias[col];
      const int row0 = m0 + wr * 64 + i * 16 + kg * 4;
      if (SM == 1) {
        float* C = (float*)Cout;
#pragma unroll
        for (int jj = 0; jj < 4; ++jj)
          C[(size_t)(row0 + jj) * N + col] = acc[i][j][jj] + bv;
      } else {
        // V transposed store: Vt[(b*16+h)*64 + dh][tok], 4 consecutive tok per lane
        u16* C = (u16*)Cout;
        const int hh = col >> 6, dh = col & 63;
        const int bb = row0 >> 11, tok = row0 & 2047;
        ushort4 o;
        o.x = f2bf(acc[i][j][0] + bv);
        o.y = f2bf(acc[i][j][1] + bv);
        o.z = f2bf(acc[i][j][2] + bv);
        o.w = f2bf(acc[i][j][3] + bv);
        *(ushort4*)(C + ((size_t)((bb * 16 + hh) * 64 + dh) * SEQ + tok)) = o;
      }
    }
  }
}

// ---------------- flash attention v5 ----------------
// Round-3 structure (buf-toggle double buffer, inline body, KVB=64, 4 blocks/CU,
// conflict-free full-rank swizzle) + exp2-only softmax (Q pre-scaled by log2e at GEMM;
// e-factor cancels) + 4-way rsum + strength-reduced stage pointers.
// NO static unroll, NO opaque-zero regs (round-4 spill suspects).
#define KVB 64
#define NT (SEQ / KVB)

__global__ __launch_bounds__(256, 4) void attn_kernel(const u16* __restrict__ Q,
                                                      const u16* __restrict__ K,
                                                      const u16* __restrict__ Vt,
                                                      u16* __restrict__ O) {
  __shared__ alignas(16) u16 Ks[2][KVB * 64]; // 2 x 8KB
  __shared__ alignas(16) u16 Vs[2][64 * KVB]; // 2 x 8KB
  const int tid = threadIdx.x;
  const int l = tid & 63;
  const int wid = tid >> 6;
  const int qg = l & 31;     // q row within wave
  const int half = l >> 5;
  // XCD-chunked grid: each XCD gets 128 consecutive swz = 8 bh values (K/V L2-resident)
  const int bid = blockIdx.x;
  const int swz = (bid & 7) * 128 + (bid >> 3);
  const int qt = swz & 15;   // 0..15
  const int bh = swz >> 4;   // 0..63
  const int b = bh >> 4, h = bh & 15;

  // ---- stage geometry: wave handles K chunks {wid, wid+4} and V chunks {wid, wid+4}
  const int srow = l >> 3, slot = l & 7;
  const int r0 = (wid << 3) + srow;
  const int r1 = ((wid + 4) << 3) + srow;
  const int sw0 = (r0 ^ (r0 >> 3)) & 7;
  const int sw1 = (r1 ^ (r1 >> 3)) & 7;
  const u16* pK0 = K + ((size_t)(b * SEQ) + r0) * D_MODEL + h * 64 + (slot ^ sw0) * 8;
  const u16* pK1 = K + ((size_t)(b * SEQ) + r1) * D_MODEL + h * 64 + (slot ^ sw1) * 8;
  const u16* pV0 = Vt + ((size_t)(bh * 64) + r0) * SEQ + (slot ^ sw0) * 8;
  const u16* pV1 = Vt + ((size_t)(bh * 64) + r1) * SEQ + (slot ^ sw1) * 8;
  const int ldsc0 = wid * 1024, ldsc1 = (wid + 4) * 1024;

  // Q fragments (pre-scaled by log2e at GEMM): col=q=l&31, k = dc*16 + half*8 + e
  bf16x8 qf[4];
  {
    const u16* q0 = Q + ((size_t)(b * SEQ + qt * 128 + wid * 32 + qg)) * D_MODEL + h * 64 + half * 8;
#pragma unroll
    for (int dc = 0; dc < 4; ++dc) qf[dc] = *(const bf16x8*)(q0 + dc * 16);
  }
  f32x16 oacc[2] = {};
  float lrun = 0.f;

  auto stage = [&](int bufi) {
    char* KsX = (char*)Ks[bufi];
    char* VsX = (char*)Vs[bufi];
    async_copy16(KsX + ldsc0, pK0);
    async_copy16(KsX + ldsc1, pK1);
    async_copy16(VsX + ldsc0, pV0);
    async_copy16(VsX + ldsc1, pV1);
    pK0 += (size_t)KVB * D_MODEL;
    pK1 += (size_t)KVB * D_MODEL;
    pV0 += KVB;
    pV1 += KVB;
  };

  stage(0);
  __syncthreads();
  int buf = 0;

  for (int t = 0; t < NT; ++t) {
    if (t + 1 < NT) stage(buf ^ 1);
    const char* KsC = (const char*)Ks[buf];
    const char* VsC = (const char*)Vs[buf];

    // S'^T[kv][q] = K·(log2e·q-hat): lane holds q=l&31, kv=(reg&3)+8*(reg>>2)+4*half (+32*t32)
    f32x16 st[2] = {};
    __builtin_amdgcn_s_setprio(1);
#pragma unroll
    for (int t32 = 0; t32 < 2; ++t32) {
      const int rowK = t32 * 32 + qg;
      const int swk = (rowK ^ (rowK >> 3)) & 7;
#pragma unroll
      for (int dc = 0; dc < 4; ++dc) {
        const int p = (dc * 2 + half) ^ swk;
        bf16x8 kf = *(const bf16x8*)(KsC + rowK * 128 + p * 16);
        st[t32] = MFMA32(kf, qf[dc], st[t32]);
      }
    }
    __builtin_amdgcn_s_setprio(0);

    // p = exp2(s')  (global e^1 factor cancels between numerator and denominator)
    float rs0 = 0.f, rs1 = 0.f, rs2 = 0.f, rs3 = 0.f;
#pragma unroll
    for (int t32 = 0; t32 < 2; ++t32)
#pragma unroll
      for (int rr = 0; rr < 16; rr += 4) {
        float p0 = __builtin_amdgcn_exp2f(st[t32][rr + 0]);
        float p1 = __builtin_amdgcn_exp2f(st[t32][rr + 1]);
        float p2 = __builtin_amdgcn_exp2f(st[t32][rr + 2]);
        float p3 = __builtin_amdgcn_exp2f(st[t32][rr + 3]);
        st[t32][rr + 0] = p0; st[t32][rr + 1] = p1;
        st[t32][rr + 2] = p2; st[t32][rr + 3] = p3;
        rs0 += p0; rs1 += p1; rs2 += p2; rs3 += p3;
      }
    lrun += (rs0 + rs1) + (rs2 + rs3);

    // PV: O^T[dh][q] += V^T[dh][kv] * P[q][kv]
#pragma unroll
    for (int t32 = 0; t32 < 2; ++t32) {
#pragma unroll
      for (int cc = 0; cc < 2; ++cc) {
        const int base = cc * 8;
        u32 wA = cvtpk_bf16(st[t32][base + 0], st[t32][base + 1]);
        u32 wB = cvtpk_bf16(st[t32][base + 2], st[t32][base + 3]);
        u32 wC = cvtpk_bf16(st[t32][base + 4], st[t32][base + 5]);
        u32 wD = cvtpk_bf16(st[t32][base + 6], st[t32][base + 7]);
        permswap(wA, wC);
        permswap(wB, wD);
        u32x4 pw = {wA, wB, wC, wD};
        bf16x8 pf = __builtin_bit_cast(bf16x8, pw);
        const int qw = ((t32 * 2 + cc) << 1) + half;
        __builtin_amdgcn_s_setprio(1);
#pragma unroll
        for (int dt = 0; dt < 2; ++dt) {
          const int rowV = dt * 32 + qg;
          const int pp = qw ^ ((rowV ^ (rowV >> 3)) & 7);
          bf16x8 vf = *(const bf16x8*)(VsC + rowV * 128 + pp * 16);
          oacc[dt] = MFMA32(vf, pf, oacc[dt]);
        }
        __builtin_amdgcn_s_setprio(0);
      }
    }
    __syncthreads();
    buf ^= 1;
  }

  // epilogue: denom = own-half sum + other-half sum; pack pairs, u32 stores
  lrun += __shfl_xor(lrun, 32);
  const float inv = 1.0f / lrun;
  u32* orow = (u32*)(O + ((size_t)(b * SEQ + qt * 128 + wid * 32 + qg)) * D_MODEL + h * 64);
#pragma unroll
  for (int dt = 0; dt < 2; ++dt)
#pragma unroll
    for (int w = 0; w < 8; ++w) {
      const int dh = dt * 32 + (w & 1) * 2 + 8 * (w >> 1) + 4 * half;
      u32 pk = cvtpk_bf16(oacc[dt][2 * w] * inv, oacc[dt][2 * w + 1] * inv);
      orow[dh >> 1] = pk;
    }
}

// ---------------- launch ----------------
extern "C" void kernel_launch(void* const* d_in, const int* in_sizes, int n_in,
                              void* d_out, int out_size, void* d_ws, size_t ws_size,
                              hipStream_t stream) {
  const float* x   = (const float*)d_in[0];
  const float* ctx = (const float*)d_in[1];
  const float* Wq  = (const float*)d_in[2];
  const float* bq  = (const float*)d_in[3];
  const float* Wk  = (const float*)d_in[4];
  const float* bk  = (const float*)d_in[5];
  const float* Wv  = (const float*)d_in[6];
  const float* bv  = (const float*)d_in[7];
  const float* Wo  = (const float*)d_in[8];
  const float* bo  = (const float*)d_in[9];
  float* out = (float*)d_out;

  const size_t NTOK = (size_t)MTOT * D_MODEL; // 8M elems
  const size_t WSZ = (size_t)D_MODEL * D_MODEL;
  u16* xb  = (u16*)d_ws;       // x bf16; later reused as attention output
  u16* cb  = xb + NTOK;
  u16* wqb = cb + NTOK;
  u16* wkb = wqb + WSZ;
  u16* wvb = wkb + WSZ;
  u16* wob = wvb + WSZ;
  u16* Qb  = wob + WSZ;
  u16* Kb  = Qb + NTOK;
  u16* Vtb = Kb + NTOK;        // [b*16+h][dh][tok]
  (void)in_sizes; (void)n_in; (void)out_size; (void)ws_size;

  dim3 blk(256);
  cvt2<<<2048, blk, 0, stream>>>(x, xb, ctx, cb, (int)(NTOK / 4));
  cvt2<<<512, blk, 0, stream>>>(Wq, wqb, Wk, wkb, (int)(WSZ / 4));
  cvt2<<<512, blk, 0, stream>>>(Wv, wvb, Wo, wob, (int)(WSZ / 4));

  gemm_bt<3><<<512, blk, 0, stream>>>(xb, wqb, bq, Qb, MTOT, D_MODEL, D_MODEL, LOG2E);
  gemm_bt<3><<<512, blk, 0, stream>>>(cb, wkb, bk, Kb, MTOT, D_MODEL, D_MODEL, 1.0f);
  gemm_bt<2><<<512, blk, 0, stream>>>(cb, wvb, bv, Vtb, MTOT, D_MODEL, D_MODEL, 0.f);

  attn_kernel<<<1024, blk, 0, stream>>>(Qb, Kb, Vtb, xb);

  gemm_bt<1><<<512, blk, 0, stream>>>(xb, wob, bo, out, MTOT, D_MODEL, D_MODEL, 0.f);
}

// Round 6
// 197.003 us; speedup vs baseline: 1.3515x; 1.0035x over previous
//
#include <hip/hip_runtime.h>

typedef unsigned short u16;
typedef unsigned int u32;
typedef __attribute__((ext_vector_type(8))) short bf16x8;
typedef __attribute__((ext_vector_type(4))) float f32x4;
typedef __attribute__((ext_vector_type(16))) float f32x16;
typedef __attribute__((ext_vector_type(4))) u32 u32x4;

#define D_MODEL 1024
#define NHEAD 16
#define DHEAD 64
#define SEQ 2048
#define BATCH 4
#define MTOT (BATCH * SEQ) /* 8192 */
#define LOG2E 1.4426950408889634f

#define MFMA16(A, B, C) __builtin_amdgcn_mfma_f32_16x16x32_bf16((A), (B), (C), 0, 0, 0)
#define MFMA32(A, B, C) __builtin_amdgcn_mfma_f32_32x32x16_bf16((A), (B), (C), 0, 0, 0)

__device__ __forceinline__ u16 f2bf(float f) {
  u32 u = __builtin_bit_cast(u32, f);
  u = (u + 0x7FFFu + ((u >> 16) & 1u)) >> 16;
  return (u16)u;
}

// async global->LDS, 16B per lane. lds must be wave-uniform; g is per-lane.
__device__ __forceinline__ void async_copy16(void* lds, const void* g) {
  __builtin_amdgcn_global_load_lds(
      (const __attribute__((address_space(1))) u32*)g,
      (__attribute__((address_space(3))) u32*)lds, 16, 0, 0);
}

__device__ __forceinline__ u32 cvtpk_bf16(float lo, float hi) {
  u32 r;
  asm("v_cvt_pk_bf16_f32 %0, %1, %2" : "=v"(r) : "v"(lo), "v"(hi));
  return r;
}
// swaps a.hi32lanes <-> b.lo32lanes
__device__ __forceinline__ void permswap(u32& a, u32& b) {
  asm("v_permlane32_swap_b32 %0, %1" : "+v"(a), "+v"(b));
}

// ---------------- fp32 -> bf16 convert (two tensors per launch) ----------------
__global__ void cvt2(const float* __restrict__ s0, u16* __restrict__ d0,
                     const float* __restrict__ s1, u16* __restrict__ d1, int n4) {
  int i = blockIdx.x * blockDim.x + threadIdx.x;
  int st = gridDim.x * blockDim.x;
  for (; i < 2 * n4; i += st) {
    const float* s = (i < n4) ? s0 : s1;
    u16* d = (i < n4) ? d0 : d1;
    int j = (i < n4) ? i : (i - n4);
    float4 v = ((const float4*)s)[j];
    ushort4 o;
    o.x = f2bf(v.x); o.y = f2bf(v.y); o.z = f2bf(v.z); o.w = f2bf(v.w);
    ((ushort4*)d)[j] = o;
  }
}

// ================= fused QKV NT-GEMM =================
// grid 1536: swz<512 -> Q = x·Wq^T (+bq, qknorm, *log2e) -> Qb
//            swz>=512 -> [K|V] = ctx·[Wk;Wv]^T; cols<1024: K (+bk, qknorm) -> Kb
//                                               cols>=1024: V (+bv, transposed) -> Vtb
__global__ __launch_bounds__(256, 3) void gemm_qkv(
    const u16* __restrict__ xb, const u16* __restrict__ cb,
    const u16* __restrict__ wqb, const u16* __restrict__ wkvb,
    const float* __restrict__ bq, const float* __restrict__ bk,
    const float* __restrict__ bv,
    u16* __restrict__ Qb, u16* __restrict__ Kb, u16* __restrict__ Vtb) {
  __shared__ u16 As[128 * 64]; // 16KB, rows 128B, granule-swizzled g^=(row&7)
  __shared__ u16 Bs[128 * 64]; // 16KB
  const int K = 1024;
  const int tid = threadIdx.x;
  const int l = tid & 63;
  const int wid = tid >> 6;
  const int bid = blockIdx.x;
  const int swz = (bid & 7) * 192 + (bid >> 3); // 1536 = 8 * 192, bijective
  const bool isQ = swz < 512;
  const u16* A;
  const u16* Bw;
  int m0, n0;
  if (isQ) {
    A = xb; Bw = wqb;
    m0 = (swz >> 3) * 128;       // 64 m-tiles
    n0 = (swz & 7) * 128;        // 8 n-tiles
  } else {
    const int s = swz - 512;
    A = cb; Bw = wkvb;
    m0 = (s >> 4) * 128;         // 64 m-tiles
    n0 = (s & 15) * 128;         // 16 n-tiles (N=2048)
  }
  const int wr = wid >> 1, wc = wid & 1;
  const int r = l & 15, kg = l >> 4;
  f32x4 acc[4][4] = {};
  char* AsB = (char*)As;
  char* BsB = (char*)Bs;
  const int arow = l >> 3;
  const int agran = (l & 7) ^ arow;

  for (int kt = 0; kt < K; kt += 64) {
#pragma unroll
    for (int cc = 0; cc < 4; ++cc) {
      int c = wid + (cc << 2);
      int rowi = (c << 3) + arow;
      const char* ga = (const char*)A + ((size_t)(m0 + rowi) * K + kt) * 2 + agran * 16;
      async_copy16(AsB + c * 1024, ga);
      const char* gb = (const char*)Bw + ((size_t)(n0 + rowi) * K + kt) * 2 + agran * 16;
      async_copy16(BsB + c * 1024, gb);
    }
    __syncthreads();
#pragma unroll
    for (int half = 0; half < 2; ++half) {
      const int g = ((half << 2) + kg) ^ (r & 7);
      bf16x8 af[4], bf[4];
#pragma unroll
      for (int i = 0; i < 4; ++i) {
        af[i] = *(const bf16x8*)(AsB + (wr * 64 + i * 16 + r) * 128 + g * 16);
        bf[i] = *(const bf16x8*)(BsB + (wc * 64 + i * 16 + r) * 128 + g * 16);
      }
#pragma unroll
      for (int i = 0; i < 4; ++i)
#pragma unroll
        for (int j = 0; j < 4; ++j)
          acc[i][j] = MFMA16(af[i], bf[j], acc[i][j]);
    }
    __syncthreads();
  }

  const int colbase = n0 + wc * 64;
  const bool isV = (!isQ) && (colbase >= 1024);
  if (!isV) {
    // qknorm epilogue (Q or K): wave owns one 64-col head group per row
    u16* C = isQ ? Qb : Kb;
    const float* bias = isQ ? bq : bk;
    const float sMul = isQ ? LOG2E : 1.0f;
    float bvj[4];
#pragma unroll
    for (int j = 0; j < 4; ++j) bvj[j] = bias[colbase + j * 16 + r];
#pragma unroll
    for (int i = 0; i < 4; ++i) {
      const int row0 = m0 + wr * 64 + i * 16 + kg * 4;
#pragma unroll
      for (int jj = 0; jj < 4; ++jj) {
        float t[4];
        float s2 = 0.f;
#pragma unroll
        for (int j = 0; j < 4; ++j) {
          t[j] = acc[i][j][jj] + bvj[j];
          s2 += t[j] * t[j];
        }
        s2 += __shfl_xor(s2, 1);
        s2 += __shfl_xor(s2, 2);
        s2 += __shfl_xor(s2, 4);
        s2 += __shfl_xor(s2, 8);
        const float inv = sMul / (sqrtf(s2) + 1e-6f);
#pragma unroll
        for (int j = 0; j < 4; ++j)
          C[(size_t)(row0 + jj) * D_MODEL + colbase + j * 16 + r] = f2bf(t[j] * inv);
      }
    }
  } else {
    // V transposed store: Vt[(b*16+h)*64 + dh][tok], 4 consecutive tok per lane
#pragma unroll
    for (int i = 0; i < 4; ++i) {
#pragma unroll
      for (int j = 0; j < 4; ++j) {
        const int col = colbase + j * 16 + r;      // 1024..2047
        const float bvv = bv[col - 1024];
        const int row0 = m0 + wr * 64 + i * 16 + kg * 4;
        const int hh = (col - 1024) >> 6, dh = col & 63;
        const int bb = row0 >> 11, tok = row0 & 2047;
        ushort4 o;
        o.x = f2bf(acc[i][j][0] + bvv);
        o.y = f2bf(acc[i][j][1] + bvv);
        o.z = f2bf(acc[i][j][2] + bvv);
        o.w = f2bf(acc[i][j][3] + bvv);
        *(ushort4*)(Vtb + ((size_t)((bb * 16 + hh) * 64 + dh) * SEQ + tok)) = o;
      }
    }
  }
}

// ================= output-projection NT-GEMM (f32 out) =================
__global__ __launch_bounds__(256, 3) void gemm_out(const u16* __restrict__ A,
                                                   const u16* __restrict__ Bw,
                                                   const float* __restrict__ bias,
                                                   float* __restrict__ Cout) {
  __shared__ u16 As[128 * 64];
  __shared__ u16 Bs[128 * 64];
  const int K = 1024, N = 1024;
  const int tid = threadIdx.x;
  const int l = tid & 63;
  const int wid = tid >> 6;
  const int bid = blockIdx.x;
  const int swz = (bid & 7) * 64 + (bid >> 3); // 512 = 8 * 64
  const int m0 = (swz >> 3) * 128;
  const int n0 = (swz & 7) * 128;
  const int wr = wid >> 1, wc = wid & 1;
  const int r = l & 15, kg = l >> 4;
  f32x4 acc[4][4] = {};
  char* AsB = (char*)As;
  char* BsB = (char*)Bs;
  const int arow = l >> 3;
  const int agran = (l & 7) ^ arow;

  for (int kt = 0; kt < K; kt += 64) {
#pragma unroll
    for (int cc = 0; cc < 4; ++cc) {
      int c = wid + (cc << 2);
      int rowi = (c << 3) + arow;
      const char* ga = (const char*)A + ((size_t)(m0 + rowi) * K + kt) * 2 + agran * 16;
      async_copy16(AsB + c * 1024, ga);
      const char* gb = (const char*)Bw + ((size_t)(n0 + rowi) * K + kt) * 2 + agran * 16;
      async_copy16(BsB + c * 1024, gb);
    }
    __syncthreads();
#pragma unroll
    for (int half = 0; half < 2; ++half) {
      const int g = ((half << 2) + kg) ^ (r & 7);
      bf16x8 af[4], bf[4];
#pragma unroll
      for (int i = 0; i < 4; ++i) {
        af[i] = *(const bf16x8*)(AsB + (wr * 64 + i * 16 + r) * 128 + g * 16);
        bf[i] = *(const bf16x8*)(BsB + (wc * 64 + i * 16 + r) * 128 + g * 16);
      }
#pragma unroll
      for (int i = 0; i < 4; ++i)
#pragma unroll
        for (int j = 0; j < 4; ++j)
          acc[i][j] = MFMA16(af[i], bf[j], acc[i][j]);
    }
    __syncthreads();
  }
#pragma unroll
  for (int i = 0; i < 4; ++i) {
#pragma unroll
    for (int j = 0; j < 4; ++j) {
      const int col = n0 + wc * 64 + j * 16 + r;
      const float bvv = bias[col];
      const int row0 = m0 + wr * 64 + i * 16 + kg * 4;
#pragma unroll
      for (int jj = 0; jj < 4; ++jj)
        Cout[(size_t)(row0 + jj) * N + col] = acc[i][j][jj] + bvv;
    }
  }
}

// ---------------- flash attention v6 ----------------
// Round-5 structure + persistent opaque-zero C-tuple (kills per-tile S-acc init).
#define KVB 64
#define NT (SEQ / KVB)

__global__ __launch_bounds__(256, 4) void attn_kernel(const u16* __restrict__ Q,
                                                      const u16* __restrict__ K,
                                                      const u16* __restrict__ Vt,
                                                      u16* __restrict__ O) {
  __shared__ alignas(16) u16 Ks[2][KVB * 64]; // 2 x 8KB
  __shared__ alignas(16) u16 Vs[2][64 * KVB]; // 2 x 8KB
  const int tid = threadIdx.x;
  const int l = tid & 63;
  const int wid = tid >> 6;
  const int qg = l & 31;     // q row within wave
  const int half = l >> 5;
  // XCD-chunked grid: each XCD gets 128 consecutive swz = 8 bh values (K/V L2-resident)
  const int bid = blockIdx.x;
  const int swz = (bid & 7) * 128 + (bid >> 3);
  const int qt = swz & 15;   // 0..15
  const int bh = swz >> 4;   // 0..63
  const int b = bh >> 4, h = bh & 15;

  // ---- stage geometry: wave handles K chunks {wid, wid+4} and V chunks {wid, wid+4}
  const int srow = l >> 3, slot = l & 7;
  const int r0 = (wid << 3) + srow;
  const int r1 = ((wid + 4) << 3) + srow;
  const int sw0 = (r0 ^ (r0 >> 3)) & 7;
  const int sw1 = (r1 ^ (r1 >> 3)) & 7;
  const u16* pK0 = K + ((size_t)(b * SEQ) + r0) * D_MODEL + h * 64 + (slot ^ sw0) * 8;
  const u16* pK1 = K + ((size_t)(b * SEQ) + r1) * D_MODEL + h * 64 + (slot ^ sw1) * 8;
  const u16* pV0 = Vt + ((size_t)(bh * 64) + r0) * SEQ + (slot ^ sw0) * 8;
  const u16* pV1 = Vt + ((size_t)(bh * 64) + r1) * SEQ + (slot ^ sw1) * 8;
  const int ldsc0 = wid * 1024, ldsc1 = (wid + 4) * 1024;

  // Q fragments (pre-scaled by log2e at GEMM): col=q=l&31, k = dc*16 + half*8 + e
  bf16x8 qf[4];
  {
    const u16* q0 = Q + ((size_t)(b * SEQ + qt * 128 + wid * 32 + qg)) * D_MODEL + h * 64 + half * 8;
#pragma unroll
    for (int dc = 0; dc < 4; ++dc) qf[dc] = *(const bf16x8*)(q0 + dc * 16);
  }
  // persistent opaque zero C-tuple (16 VGPR; avoids per-tile S-acc zero-init)
  float z0 = 0.f;
  asm("" : "+v"(z0));
  f32x16 zc;
#pragma unroll
  for (int i = 0; i < 16; ++i) zc[i] = z0;

  f32x16 oacc[2] = {};
  float lrun = 0.f;

  auto stage = [&](int bufi) {
    char* KsX = (char*)Ks[bufi];
    char* VsX = (char*)Vs[bufi];
    async_copy16(KsX + ldsc0, pK0);
    async_copy16(KsX + ldsc1, pK1);
    async_copy16(VsX + ldsc0, pV0);
    async_copy16(VsX + ldsc1, pV1);
    pK0 += (size_t)KVB * D_MODEL;
    pK1 += (size_t)KVB * D_MODEL;
    pV0 += KVB;
    pV1 += KVB;
  };

  stage(0);
  __syncthreads();
  int buf = 0;

  for (int t = 0; t < NT; ++t) {
    if (t + 1 < NT) stage(buf ^ 1);
    const char* KsC = (const char*)Ks[buf];
    const char* VsC = (const char*)Vs[buf];

    // S'^T[kv][q] = K·(log2e·q-hat): lane holds q=l&31, kv=(reg&3)+8*(reg>>2)+4*half (+32*t32)
    f32x16 st[2];
    __builtin_amdgcn_s_setprio(1);
#pragma unroll
    for (int t32 = 0; t32 < 2; ++t32) {
      const int rowK = t32 * 32 + qg;
      const int swk = (rowK ^ (rowK >> 3)) & 7;
      bf16x8 kf0 = *(const bf16x8*)(KsC + rowK * 128 + (half ^ swk) * 16);
      st[t32] = MFMA32(kf0, qf[0], zc);
#pragma unroll
      for (int dc = 1; dc < 4; ++dc) {
        const int p = (dc * 2 + half) ^ swk;
        bf16x8 kf = *(const bf16x8*)(KsC + rowK * 128 + p * 16);
        st[t32] = MFMA32(kf, qf[dc], st[t32]);
      }
    }
    __builtin_amdgcn_s_setprio(0);

    // p = exp2(s')  (global e^1 factor cancels between numerator and denominator)
    float rs0 = 0.f, rs1 = 0.f, rs2 = 0.f, rs3 = 0.f;
#pragma unroll
    for (int t32 = 0; t32 < 2; ++t32)
#pragma unroll
      for (int rr = 0; rr < 16; rr += 4) {
        float p0 = __builtin_amdgcn_exp2f(st[t32][rr + 0]);
        float p1 = __builtin_amdgcn_exp2f(st[t32][rr + 1]);
        float p2 = __builtin_amdgcn_exp2f(st[t32][rr + 2]);
        float p3 = __builtin_amdgcn_exp2f(st[t32][rr + 3]);
        st[t32][rr + 0] = p0; st[t32][rr + 1] = p1;
        st[t32][rr + 2] = p2; st[t32][rr + 3] = p3;
        rs0 += p0; rs1 += p1; rs2 += p2; rs3 += p3;
      }
    lrun += (rs0 + rs1) + (rs2 + rs3);

    // PV: O^T[dh][q] += V^T[dh][kv] * P[q][kv]
#pragma unroll
    for (int t32 = 0; t32 < 2; ++t32) {
#pragma unroll
      for (int cc = 0; cc < 2; ++cc) {
        const int base = cc * 8;
        u32 wA = cvtpk_bf16(st[t32][base + 0], st[t32][base + 1]);
        u32 wB = cvtpk_bf16(st[t32][base + 2], st[t32][base + 3]);
        u32 wC = cvtpk_bf16(st[t32][base + 4], st[t32][base + 5]);
        u32 wD = cvtpk_bf16(st[t32][base + 6], st[t32][base + 7]);
        permswap(wA, wC);
        permswap(wB, wD);
        u32x4 pw = {wA, wB, wC, wD};
        bf16x8 pf = __builtin_bit_cast(bf16x8, pw);
        const int qw = ((t32 * 2 + cc) << 1) + half;
        __builtin_amdgcn_s_setprio(1);
#pragma unroll
        for (int dt = 0; dt < 2; ++dt) {
          const int rowV = dt * 32 + qg;
          const int pp = qw ^ ((rowV ^ (rowV >> 3)) & 7);
          bf16x8 vf = *(const bf16x8*)(VsC + rowV * 128 + pp * 16);
          oacc[dt] = MFMA32(vf, pf, oacc[dt]);
        }
        __builtin_amdgcn_s_setprio(0);
      }
    }
    __syncthreads();
    buf ^= 1;
  }

  // epilogue: denom = own-half sum + other-half sum; pack pairs, u32 stores
  lrun += __shfl_xor(lrun, 32);
  const float inv = 1.0f / lrun;
  u32* orow = (u32*)(O + ((size_t)(b * SEQ + qt * 128 + wid * 32 + qg)) * D_MODEL + h * 64);
#pragma unroll
  for (int dt = 0; dt < 2; ++dt)
#pragma unroll
    for (int w = 0; w < 8; ++w) {
      const int dh = dt * 32 + (w & 1) * 2 + 8 * (w >> 1) + 4 * half;
      u32 pk = cvtpk_bf16(oacc[dt][2 * w] * inv, oacc[dt][2 * w + 1] * inv);
      orow[dh >> 1] = pk;
    }
}

// ---------------- launch ----------------
extern "C" void kernel_launch(void* const* d_in, const int* in_sizes, int n_in,
                              void* d_out, int out_size, void* d_ws, size_t ws_size,
                              hipStream_t stream) {
  const float* x   = (const float*)d_in[0];
  const float* ctx = (const float*)d_in[1];
  const float* Wq  = (const float*)d_in[2];
  const float* bq  = (const float*)d_in[3];
  const float* Wk  = (const float*)d_in[4];
  const float* bk  = (const float*)d_in[5];
  const float* Wv  = (const float*)d_in[6];
  const float* bv  = (const float*)d_in[7];
  const float* Wo  = (const float*)d_in[8];
  const float* bo  = (const float*)d_in[9];
  float* out = (float*)d_out;

  const size_t NTOK = (size_t)MTOT * D_MODEL; // 8M elems
  const size_t WSZ = (size_t)D_MODEL * D_MODEL;
  u16* xb  = (u16*)d_ws;       // x bf16; later reused as attention output
  u16* cb  = xb + NTOK;
  u16* wqb = cb + NTOK;
  u16* wkb = wqb + WSZ;        // wk,wv adjacent -> fused [K|V] GEMM B-panel
  u16* wvb = wkb + WSZ;
  u16* wob = wvb + WSZ;
  u16* Qb  = wob + WSZ;
  u16* Kb  = Qb + NTOK;
  u16* Vtb = Kb + NTOK;        // [b*16+h][dh][tok]
  (void)in_sizes; (void)n_in; (void)out_size; (void)ws_size;

  dim3 blk(256);
  cvt2<<<2048, blk, 0, stream>>>(x, xb, ctx, cb, (int)(NTOK / 4));
  cvt2<<<512, blk, 0, stream>>>(Wq, wqb, Wk, wkb, (int)(WSZ / 4));
  cvt2<<<512, blk, 0, stream>>>(Wv, wvb, Wo, wob, (int)(WSZ / 4));

  gemm_qkv<<<1536, blk, 0, stream>>>(xb, cb, wqb, wkb, bq, bk, bv, Qb, Kb, Vtb);

  attn_kernel<<<1024, blk, 0, stream>>>(Qb, Kb, Vtb, xb);

  gemm_out<<<512, blk, 0, stream>>>(xb, wob, bo, out);
}

// Round 7
// 182.293 us; speedup vs baseline: 1.4606x; 1.0807x over previous
//
#include <hip/hip_runtime.h>

typedef unsigned short u16;
typedef unsigned int u32;
typedef __attribute__((ext_vector_type(8))) short bf16x8;
typedef __attribute__((ext_vector_type(4))) float f32x4;
typedef __attribute__((ext_vector_type(16))) float f32x16;
typedef __attribute__((ext_vector_type(4))) u32 u32x4;

#define D_MODEL 1024
#define NHEAD 16
#define DHEAD 64
#define SEQ 2048
#define BATCH 4
#define MTOT (BATCH * SEQ) /* 8192 */
#define LOG2E 1.4426950408889634f

#define MFMA16(A, B, C) __builtin_amdgcn_mfma_f32_16x16x32_bf16((A), (B), (C), 0, 0, 0)
#define MFMA32(A, B, C) __builtin_amdgcn_mfma_f32_32x32x16_bf16((A), (B), (C), 0, 0, 0)

__device__ __forceinline__ u16 f2bf(float f) {
  u32 u = __builtin_bit_cast(u32, f);
  u = (u + 0x7FFFu + ((u >> 16) & 1u)) >> 16;
  return (u16)u;
}

// async global->LDS, 16B per lane. lds must be wave-uniform; g is per-lane.
__device__ __forceinline__ void async_copy16(void* lds, const void* g) {
  __builtin_amdgcn_global_load_lds(
      (const __attribute__((address_space(1))) u32*)g,
      (__attribute__((address_space(3))) u32*)lds, 16, 0, 0);
}

__device__ __forceinline__ u32 cvtpk_bf16(float lo, float hi) {
  u32 r;
  asm("v_cvt_pk_bf16_f32 %0, %1, %2" : "=v"(r) : "v"(lo), "v"(hi));
  return r;
}
// swaps a.hi32lanes <-> b.lo32lanes
__device__ __forceinline__ void permswap(u32& a, u32& b) {
  asm("v_permlane32_swap_b32 %0, %1" : "+v"(a), "+v"(b));
}

// ---------------- fp32 -> bf16 convert (two tensors per launch) ----------------
__global__ void cvt2(const float* __restrict__ s0, u16* __restrict__ d0,
                     const float* __restrict__ s1, u16* __restrict__ d1, int n4) {
  int i = blockIdx.x * blockDim.x + threadIdx.x;
  int st = gridDim.x * blockDim.x;
  for (; i < 2 * n4; i += st) {
    const float* s = (i < n4) ? s0 : s1;
    u16* d = (i < n4) ? d0 : d1;
    int j = (i < n4) ? i : (i - n4);
    float4 v = ((const float4*)s)[j];
    ushort4 o;
    o.x = f2bf(v.x); o.y = f2bf(v.y); o.z = f2bf(v.z); o.w = f2bf(v.w);
    ((ushort4*)d)[j] = o;
  }
}

// ================= fused QKV NT-GEMM =================
// grid 1536: swz<512 -> Q = x·Wq^T (+bq, qknorm, *log2e) -> Qb
//            swz>=512 -> [K|V] = ctx·[Wk;Wv]^T; cols<1024: K (+bk, qknorm) -> Kb
//                                               cols>=1024: V (+bv, transposed) -> Vtb
__global__ __launch_bounds__(256, 3) void gemm_qkv(
    const u16* __restrict__ xb, const u16* __restrict__ cb,
    const u16* __restrict__ wqb, const u16* __restrict__ wkvb,
    const float* __restrict__ bq, const float* __restrict__ bk,
    const float* __restrict__ bv,
    u16* __restrict__ Qb, u16* __restrict__ Kb, u16* __restrict__ Vtb) {
  __shared__ u16 As[128 * 64]; // 16KB, rows 128B, granule-swizzled g^=(row&7)
  __shared__ u16 Bs[128 * 64]; // 16KB
  const int K = 1024;
  const int tid = threadIdx.x;
  const int l = tid & 63;
  const int wid = tid >> 6;
  const int bid = blockIdx.x;
  const int swz = (bid & 7) * 192 + (bid >> 3); // 1536 = 8 * 192, bijective
  const bool isQ = swz < 512;
  const u16* A;
  const u16* Bw;
  int m0, n0;
  if (isQ) {
    A = xb; Bw = wqb;
    m0 = (swz >> 3) * 128;       // 64 m-tiles
    n0 = (swz & 7) * 128;        // 8 n-tiles
  } else {
    const int s = swz - 512;
    A = cb; Bw = wkvb;
    m0 = (s >> 4) * 128;         // 64 m-tiles
    n0 = (s & 15) * 128;         // 16 n-tiles (N=2048)
  }
  const int wr = wid >> 1, wc = wid & 1;
  const int r = l & 15, kg = l >> 4;
  f32x4 acc[4][4] = {};
  char* AsB = (char*)As;
  char* BsB = (char*)Bs;
  const int arow = l >> 3;
  const int agran = (l & 7) ^ arow;

  for (int kt = 0; kt < K; kt += 64) {
#pragma unroll
    for (int cc = 0; cc < 4; ++cc) {
      int c = wid + (cc << 2);
      int rowi = (c << 3) + arow;
      const char* ga = (const char*)A + ((size_t)(m0 + rowi) * K + kt) * 2 + agran * 16;
      async_copy16(AsB + c * 1024, ga);
      const char* gb = (const char*)Bw + ((size_t)(n0 + rowi) * K + kt) * 2 + agran * 16;
      async_copy16(BsB + c * 1024, gb);
    }
    __syncthreads();
#pragma unroll
    for (int half = 0; half < 2; ++half) {
      const int g = ((half << 2) + kg) ^ (r & 7);
      bf16x8 af[4], bf[4];
#pragma unroll
      for (int i = 0; i < 4; ++i) {
        af[i] = *(const bf16x8*)(AsB + (wr * 64 + i * 16 + r) * 128 + g * 16);
        bf[i] = *(const bf16x8*)(BsB + (wc * 64 + i * 16 + r) * 128 + g * 16);
      }
#pragma unroll
      for (int i = 0; i < 4; ++i)
#pragma unroll
        for (int j = 0; j < 4; ++j)
          acc[i][j] = MFMA16(af[i], bf[j], acc[i][j]);
    }
    __syncthreads();
  }

  const int colbase = n0 + wc * 64;
  const bool isV = (!isQ) && (colbase >= 1024);
  if (!isV) {
    // qknorm epilogue (Q or K): wave owns one 64-col head group per row
    u16* C = isQ ? Qb : Kb;
    const float* bias = isQ ? bq : bk;
    const float sMul = isQ ? LOG2E : 1.0f;
    float bvj[4];
#pragma unroll
    for (int j = 0; j < 4; ++j) bvj[j] = bias[colbase + j * 16 + r];
#pragma unroll
    for (int i = 0; i < 4; ++i) {
      const int row0 = m0 + wr * 64 + i * 16 + kg * 4;
#pragma unroll
      for (int jj = 0; jj < 4; ++jj) {
        float t[4];
        float s2 = 0.f;
#pragma unroll
        for (int j = 0; j < 4; ++j) {
          t[j] = acc[i][j][jj] + bvj[j];
          s2 += t[j] * t[j];
        }
        s2 += __shfl_xor(s2, 1);
        s2 += __shfl_xor(s2, 2);
        s2 += __shfl_xor(s2, 4);
        s2 += __shfl_xor(s2, 8);
        const float inv = sMul / (sqrtf(s2) + 1e-6f);
#pragma unroll
        for (int j = 0; j < 4; ++j)
          C[(size_t)(row0 + jj) * D_MODEL + colbase + j * 16 + r] = f2bf(t[j] * inv);
      }
    }
  } else {
    // V transposed store: Vt[(b*16+h)*64 + dh][tok], 4 consecutive tok per lane
#pragma unroll
    for (int i = 0; i < 4; ++i) {
#pragma unroll
      for (int j = 0; j < 4; ++j) {
        const int col = colbase + j * 16 + r;      // 1024..2047
        const float bvv = bv[col - 1024];
        const int row0 = m0 + wr * 64 + i * 16 + kg * 4;
        const int hh = (col - 1024) >> 6, dh = col & 63;
        const int bb = row0 >> 11, tok = row0 & 2047;
        ushort4 o;
        o.x = f2bf(acc[i][j][0] + bvv);
        o.y = f2bf(acc[i][j][1] + bvv);
        o.z = f2bf(acc[i][j][2] + bvv);
        o.w = f2bf(acc[i][j][3] + bvv);
        *(ushort4*)(Vtb + ((size_t)((bb * 16 + hh) * 64 + dh) * SEQ + tok)) = o;
      }
    }
  }
}

// ================= output-projection NT-GEMM (f32 out) =================
__global__ __launch_bounds__(256, 3) void gemm_out(const u16* __restrict__ A,
                                                   const u16* __restrict__ Bw,
                                                   const float* __restrict__ bias,
                                                   float* __restrict__ Cout) {
  __shared__ u16 As[128 * 64];
  __shared__ u16 Bs[128 * 64];
  const int K = 1024, N = 1024;
  const int tid = threadIdx.x;
  const int l = tid & 63;
  const int wid = tid >> 6;
  const int bid = blockIdx.x;
  const int swz = (bid & 7) * 64 + (bid >> 3); // 512 = 8 * 64
  const int m0 = (swz >> 3) * 128;
  const int n0 = (swz & 7) * 128;
  const int wr = wid >> 1, wc = wid & 1;
  const int r = l & 15, kg = l >> 4;
  f32x4 acc[4][4] = {};
  char* AsB = (char*)As;
  char* BsB = (char*)Bs;
  const int arow = l >> 3;
  const int agran = (l & 7) ^ arow;

  for (int kt = 0; kt < K; kt += 64) {
#pragma unroll
    for (int cc = 0; cc < 4; ++cc) {
      int c = wid + (cc << 2);
      int rowi = (c << 3) + arow;
      const char* ga = (const char*)A + ((size_t)(m0 + rowi) * K + kt) * 2 + agran * 16;
      async_copy16(AsB + c * 1024, ga);
      const char* gb = (const char*)Bw + ((size_t)(n0 + rowi) * K + kt) * 2 + agran * 16;
      async_copy16(BsB + c * 1024, gb);
    }
    __syncthreads();
#pragma unroll
    for (int half = 0; half < 2; ++half) {
      const int g = ((half << 2) + kg) ^ (r & 7);
      bf16x8 af[4], bf[4];
#pragma unroll
      for (int i = 0; i < 4; ++i) {
        af[i] = *(const bf16x8*)(AsB + (wr * 64 + i * 16 + r) * 128 + g * 16);
        bf[i] = *(const bf16x8*)(BsB + (wc * 64 + i * 16 + r) * 128 + g * 16);
      }
#pragma unroll
      for (int i = 0; i < 4; ++i)
#pragma unroll
        for (int j = 0; j < 4; ++j)
          acc[i][j] = MFMA16(af[i], bf[j], acc[i][j]);
    }
    __syncthreads();
  }
#pragma unroll
  for (int i = 0; i < 4; ++i) {
#pragma unroll
    for (int j = 0; j < 4; ++j) {
      const int col = n0 + wc * 64 + j * 16 + r;
      const float bvv = bias[col];
      const int row0 = m0 + wr * 64 + i * 16 + kg * 4;
#pragma unroll
      for (int jj = 0; jj < 4; ++jj)
        Cout[(size_t)(row0 + jj) * N + col] = acc[i][j][jj] + bvv;
    }
  }
}

// ---------------- flash attention v5 (round-5 exact: best measured 82.5 us) ----------------
// KVB=64, 4 blocks/CU, conflict-free full-rank swizzle, buf-toggle double buffer,
// exp2-only softmax (Q pre-scaled by log2e at GEMM; e-factor cancels), 4-way rsum,
// strength-reduced stage pointers. NO opaque-zero C-tuple (regressed twice: r4 spill, r6 stall).
#define KVB 64
#define NT (SEQ / KVB)

__global__ __launch_bounds__(256, 4) void attn_kernel(const u16* __restrict__ Q,
                                                      const u16* __restrict__ K,
                                                      const u16* __restrict__ Vt,
                                                      u16* __restrict__ O) {
  __shared__ alignas(16) u16 Ks[2][KVB * 64]; // 2 x 8KB
  __shared__ alignas(16) u16 Vs[2][64 * KVB]; // 2 x 8KB
  const int tid = threadIdx.x;
  const int l = tid & 63;
  const int wid = tid >> 6;
  const int qg = l & 31;     // q row within wave
  const int half = l >> 5;
  // XCD-chunked grid: each XCD gets 128 consecutive swz = 8 bh values (K/V L2-resident)
  const int bid = blockIdx.x;
  const int swz = (bid & 7) * 128 + (bid >> 3);
  const int qt = swz & 15;   // 0..15
  const int bh = swz >> 4;   // 0..63
  const int b = bh >> 4, h = bh & 15;

  // ---- stage geometry: wave handles K chunks {wid, wid+4} and V chunks {wid, wid+4}
  const int srow = l >> 3, slot = l & 7;
  const int r0 = (wid << 3) + srow;
  const int r1 = ((wid + 4) << 3) + srow;
  const int sw0 = (r0 ^ (r0 >> 3)) & 7;
  const int sw1 = (r1 ^ (r1 >> 3)) & 7;
  const u16* pK0 = K + ((size_t)(b * SEQ) + r0) * D_MODEL + h * 64 + (slot ^ sw0) * 8;
  const u16* pK1 = K + ((size_t)(b * SEQ) + r1) * D_MODEL + h * 64 + (slot ^ sw1) * 8;
  const u16* pV0 = Vt + ((size_t)(bh * 64) + r0) * SEQ + (slot ^ sw0) * 8;
  const u16* pV1 = Vt + ((size_t)(bh * 64) + r1) * SEQ + (slot ^ sw1) * 8;
  const int ldsc0 = wid * 1024, ldsc1 = (wid + 4) * 1024;

  // Q fragments (pre-scaled by log2e at GEMM): col=q=l&31, k = dc*16 + half*8 + e
  bf16x8 qf[4];
  {
    const u16* q0 = Q + ((size_t)(b * SEQ + qt * 128 + wid * 32 + qg)) * D_MODEL + h * 64 + half * 8;
#pragma unroll
    for (int dc = 0; dc < 4; ++dc) qf[dc] = *(const bf16x8*)(q0 + dc * 16);
  }
  f32x16 oacc[2] = {};
  float lrun = 0.f;

  auto stage = [&](int bufi) {
    char* KsX = (char*)Ks[bufi];
    char* VsX = (char*)Vs[bufi];
    async_copy16(KsX + ldsc0, pK0);
    async_copy16(KsX + ldsc1, pK1);
    async_copy16(VsX + ldsc0, pV0);
    async_copy16(VsX + ldsc1, pV1);
    pK0 += (size_t)KVB * D_MODEL;
    pK1 += (size_t)KVB * D_MODEL;
    pV0 += KVB;
    pV1 += KVB;
  };

  stage(0);
  __syncthreads();
  int buf = 0;

  for (int t = 0; t < NT; ++t) {
    if (t + 1 < NT) stage(buf ^ 1);
    const char* KsC = (const char*)Ks[buf];
    const char* VsC = (const char*)Vs[buf];

    // S'^T[kv][q] = K·(log2e·q-hat): lane holds q=l&31, kv=(reg&3)+8*(reg>>2)+4*half (+32*t32)
    f32x16 st[2] = {};
    __builtin_amdgcn_s_setprio(1);
#pragma unroll
    for (int t32 = 0; t32 < 2; ++t32) {
      const int rowK = t32 * 32 + qg;
      const int swk = (rowK ^ (rowK >> 3)) & 7;
#pragma unroll
      for (int dc = 0; dc < 4; ++dc) {
        const int p = (dc * 2 + half) ^ swk;
        bf16x8 kf = *(const bf16x8*)(KsC + rowK * 128 + p * 16);
        st[t32] = MFMA32(kf, qf[dc], st[t32]);
      }
    }
    __builtin_amdgcn_s_setprio(0);

    // p = exp2(s')  (global e^1 factor cancels between numerator and denominator)
    float rs0 = 0.f, rs1 = 0.f, rs2 = 0.f, rs3 = 0.f;
#pragma unroll
    for (int t32 = 0; t32 < 2; ++t32)
#pragma unroll
      for (int rr = 0; rr < 16; rr += 4) {
        float p0 = __builtin_amdgcn_exp2f(st[t32][rr + 0]);
        float p1 = __builtin_amdgcn_exp2f(st[t32][rr + 1]);
        float p2 = __builtin_amdgcn_exp2f(st[t32][rr + 2]);
        float p3 = __builtin_amdgcn_exp2f(st[t32][rr + 3]);
        st[t32][rr + 0] = p0; st[t32][rr + 1] = p1;
        st[t32][rr + 2] = p2; st[t32][rr + 3] = p3;
        rs0 += p0; rs1 += p1; rs2 += p2; rs3 += p3;
      }
    lrun += (rs0 + rs1) + (rs2 + rs3);

    // PV: O^T[dh][q] += V^T[dh][kv] * P[q][kv]
#pragma unroll
    for (int t32 = 0; t32 < 2; ++t32) {
#pragma unroll
      for (int cc = 0; cc < 2; ++cc) {
        const int base = cc * 8;
        u32 wA = cvtpk_bf16(st[t32][base + 0], st[t32][base + 1]);
        u32 wB = cvtpk_bf16(st[t32][base + 2], st[t32][base + 3]);
        u32 wC = cvtpk_bf16(st[t32][base + 4], st[t32][base + 5]);
        u32 wD = cvtpk_bf16(st[t32][base + 6], st[t32][base + 7]);
        permswap(wA, wC);
        permswap(wB, wD);
        u32x4 pw = {wA, wB, wC, wD};
        bf16x8 pf = __builtin_bit_cast(bf16x8, pw);
        const int qw = ((t32 * 2 + cc) << 1) + half;
        __builtin_amdgcn_s_setprio(1);
#pragma unroll
        for (int dt = 0; dt < 2; ++dt) {
          const int rowV = dt * 32 + qg;
          const int pp = qw ^ ((rowV ^ (rowV >> 3)) & 7);
          bf16x8 vf = *(const bf16x8*)(VsC + rowV * 128 + pp * 16);
          oacc[dt] = MFMA32(vf, pf, oacc[dt]);
        }
        __builtin_amdgcn_s_setprio(0);
      }
    }
    __syncthreads();
    buf ^= 1;
  }

  // epilogue: denom = own-half sum + other-half sum; pack pairs, u32 stores
  lrun += __shfl_xor(lrun, 32);
  const float inv = 1.0f / lrun;
  u32* orow = (u32*)(O + ((size_t)(b * SEQ + qt * 128 + wid * 32 + qg)) * D_MODEL + h * 64);
#pragma unroll
  for (int dt = 0; dt < 2; ++dt)
#pragma unroll
    for (int w = 0; w < 8; ++w) {
      const int dh = dt * 32 + (w & 1) * 2 + 8 * (w >> 1) + 4 * half;
      u32 pk = cvtpk_bf16(oacc[dt][2 * w] * inv, oacc[dt][2 * w + 1] * inv);
      orow[dh >> 1] = pk;
    }
}

// ---------------- launch ----------------
extern "C" void kernel_launch(void* const* d_in, const int* in_sizes, int n_in,
                              void* d_out, int out_size, void* d_ws, size_t ws_size,
                              hipStream_t stream) {
  const float* x   = (const float*)d_in[0];
  const float* ctx = (const float*)d_in[1];
  const float* Wq  = (const float*)d_in[2];
  const float* bq  = (const float*)d_in[3];
  const float* Wk  = (const float*)d_in[4];
  const float* bk  = (const float*)d_in[5];
  const float* Wv  = (const float*)d_in[6];
  const float* bv  = (const float*)d_in[7];
  const float* Wo  = (const float*)d_in[8];
  const float* bo  = (const float*)d_in[9];
  float* out = (float*)d_out;

  const size_t NTOK = (size_t)MTOT * D_MODEL; // 8M elems
  const size_t WSZ = (size_t)D_MODEL * D_MODEL;
  u16* xb  = (u16*)d_ws;       // x bf16; later reused as attention output
  u16* cb  = xb + NTOK;
  u16* wqb = cb + NTOK;
  u16* wkb = wqb + WSZ;        // wk,wv adjacent -> fused [K|V] GEMM B-panel
  u16* wvb = wkb + WSZ;
  u16* wob = wvb + WSZ;
  u16* Qb  = wob + WSZ;
  u16* Kb  = Qb + NTOK;
  u16* Vtb = Kb + NTOK;        // [b*16+h][dh][tok]
  (void)in_sizes; (void)n_in; (void)out_size; (void)ws_size;

  dim3 blk(256);
  cvt2<<<2048, blk, 0, stream>>>(x, xb, ctx, cb, (int)(NTOK / 4));
  cvt2<<<512, blk, 0, stream>>>(Wq, wqb, Wk, wkb, (int)(WSZ / 4));
  cvt2<<<512, blk, 0, stream>>>(Wv, wvb, Wo, wob, (int)(WSZ / 4));

  gemm_qkv<<<1536, blk, 0, stream>>>(xb, cb, wqb, wkb, bq, bk, bv, Qb, Kb, Vtb);

  attn_kernel<<<1024, blk, 0, stream>>>(Qb, Kb, Vtb, xb);

  gemm_out<<<512, blk, 0, stream>>>(xb, wob, bo, out);
}